// Round 1
// 732.484 us; speedup vs baseline: 1.0805x; 1.0805x over previous
//
#include <hip/hip_runtime.h>
#include <stdint.h>
#include <stddef.h>

// ---------------------------------------------------------------------------
// InverseImportanceLinear: out = x @ W_deq^T + bias
//   W_deq[k,n] = (Q[k,n] - zeros[k,n/64]) * scales[k,n/64] * mu2[k] * mu1[n]
// Phase 1: dequant W -> bf16 workspace, convert x -> bf16 workspace.
// Phase 2: 256x256-tile 8-phase bf16 MFMA GEMM (T2 swizzle + T3/T4 counted
// vmcnt + T5 setprio + T1 XCD swizzle), bias fused in epilogue.
// ---------------------------------------------------------------------------

typedef __attribute__((ext_vector_type(8))) short bfrag;   // 8 bf16 = 4 VGPRs
typedef __attribute__((ext_vector_type(4))) float f32x4;
typedef __attribute__((ext_vector_type(4))) int   i32x4;

__device__ __forceinline__ short f2bf(float f) {
    uint32_t u = __float_as_uint(f);
    u += 0x7fffu + ((u >> 16) & 1u);        // round-to-nearest-even
    return (short)(u >> 16);
}

__device__ __forceinline__ void gload_lds16(const void* g, void* l) {
    __builtin_amdgcn_global_load_lds(
        (const __attribute__((address_space(1))) void*)g,
        (__attribute__((address_space(3))) void*)l,
        16, 0, 0);
}

// ---- phase 1a: x fp32 -> bf16 (16 elems / thread) ------------------------
__global__ void cvt_x_kernel(const float* __restrict__ x, short* __restrict__ xb) {
    size_t i = (size_t)blockIdx.x * 256 + threadIdx.x;   // 16-elem chunk index
    const f32x4* xv = (const f32x4*)x + 4 * i;
    f32x4 a = xv[0], b = xv[1], c = xv[2], d = xv[3];
    bfrag o0, o1;
    o0[0] = f2bf(a[0]); o0[1] = f2bf(a[1]); o0[2] = f2bf(a[2]); o0[3] = f2bf(a[3]);
    o0[4] = f2bf(b[0]); o0[5] = f2bf(b[1]); o0[6] = f2bf(b[2]); o0[7] = f2bf(b[3]);
    o1[0] = f2bf(c[0]); o1[1] = f2bf(c[1]); o1[2] = f2bf(c[2]); o1[3] = f2bf(c[3]);
    o1[4] = f2bf(d[0]); o1[5] = f2bf(d[1]); o1[6] = f2bf(d[2]); o1[7] = f2bf(d[3]);
    bfrag* ov = (bfrag*)xb + 2 * i;
    ov[0] = o0; ov[1] = o1;
}

// ---- phase 1b: dequant W -> bf16, one block per row, 16 elems/thread -----
__global__ void deq_w_kernel(const int* __restrict__ Q,
                             const float* __restrict__ scales,
                             const float* __restrict__ zeros,
                             const float* __restrict__ mu1,
                             const float* __restrict__ mu2,
                             short* __restrict__ wb,
                             int k0, int N, int NG) {
    const int kl = blockIdx.x;
    const int kg = k0 + kl;
    const int t  = threadIdx.x;          // 256 threads * 16 elems = 4096 = N
    const int n0 = t << 4;
    const int g  = n0 >> 6;              // GROUP_SIZE=64, 16 | 64 -> one group
    const float s = scales[(size_t)kg * NG + g] * mu2[kg];
    const float z = zeros[(size_t)kg * NG + g];
    const i32x4* qv = (const i32x4*)(Q + (size_t)kg * N + n0);
    const f32x4* uv = (const f32x4*)(mu1 + n0);
    i32x4 q0 = qv[0], q1 = qv[1], q2 = qv[2], q3 = qv[3];
    f32x4 u0 = uv[0], u1 = uv[1], u2 = uv[2], u3 = uv[3];
    bfrag o0, o1;
    o0[0] = f2bf(((float)q0[0] - z) * s * u0[0]);
    o0[1] = f2bf(((float)q0[1] - z) * s * u0[1]);
    o0[2] = f2bf(((float)q0[2] - z) * s * u0[2]);
    o0[3] = f2bf(((float)q0[3] - z) * s * u0[3]);
    o0[4] = f2bf(((float)q1[0] - z) * s * u1[0]);
    o0[5] = f2bf(((float)q1[1] - z) * s * u1[1]);
    o0[6] = f2bf(((float)q1[2] - z) * s * u1[2]);
    o0[7] = f2bf(((float)q1[3] - z) * s * u1[3]);
    o1[0] = f2bf(((float)q2[0] - z) * s * u2[0]);
    o1[1] = f2bf(((float)q2[1] - z) * s * u2[1]);
    o1[2] = f2bf(((float)q2[2] - z) * s * u2[2]);
    o1[3] = f2bf(((float)q2[3] - z) * s * u2[3]);
    o1[4] = f2bf(((float)q3[0] - z) * s * u3[0]);
    o1[5] = f2bf(((float)q3[1] - z) * s * u3[1]);
    o1[6] = f2bf(((float)q3[2] - z) * s * u3[2]);
    o1[7] = f2bf(((float)q3[3] - z) * s * u3[3]);
    bfrag* ov = (bfrag*)(wb + (size_t)kl * N + n0);
    ov[0] = o0; ov[1] = o1;
}

// ---- phase 2: 256x256 8-phase bf16 GEMM, C = A @ B^T + bias --------------
// A: M x Kc bf16 row-major (x). B: rows x Kc bf16 row-major (W chunk).
// 512 threads = 8 waves (2 M x 4 N); per-wave 128x64 output; BK=64.
// LDS 128 KiB: buf{0,1} x { A 32 KiB | B 32 KiB }, XOR-swizzled
// (read byte col ^= (row&7)<<4; inverse swizzle applied on global src).

__global__ __launch_bounds__(512, 2)
void gemm8p_kernel(const short* __restrict__ A, const short* __restrict__ B,
                   const float* __restrict__ bias, float* __restrict__ C,
                   int Kc, int Nout, int col0, int GX) {
    extern __shared__ __attribute__((aligned(16))) char smem[];   // 131072 B

    const int tid  = threadIdx.x;
    const int lane = tid & 63;
    const int wid  = tid >> 6;
    const int wm   = wid >> 2;              // 0..1
    const int wn   = wid & 3;               // 0..3
    const int r    = lane & 15;
    const int hib  = (lane >> 4) << 4;      // k-fragment byte offset
    const int sw   = (r & 7) << 4;          // read-side XOR swizzle

    // XCD-aware bijective swizzle (grid size is GX*16, multiple of 8)
    const int nwg = (int)gridDim.x;
    const int cpx = nwg >> 3;
    const int bid = (int)blockIdx.x;
    const int swz = (bid & 7) * cpx + (bid >> 3);
    const int bx  = swz % GX;               // over B rows (C cols)
    const int by  = swz / GX;               // over A rows
    const int bm  = by * 256;
    const int bnl = bx * 256;

    const int KB = Kc * 2;                  // row stride in bytes (8192)
    // staging source: thread covers row (tid>>3), 16B granule (tid&7),
    // with inverse swizzle folded into the global column.
    const int swcol = ((tid ^ (tid >> 3)) & 7) << 4;
    const char* srcA = (const char*)A + (size_t)(bm  + (tid >> 3)) * KB + swcol;
    const char* srcB = (const char*)B + (size_t)(bnl + (tid >> 3)) * KB + swcol;

    f32x4 acc[8][4];
#pragma unroll
    for (int i = 0; i < 8; i++)
#pragma unroll
        for (int j = 0; j < 4; j++)
            acc[i][j] = (f32x4){0.f, 0.f, 0.f, 0.f};

    const int NT = Kc / 64;                 // K-tiles (even; Kc % 128 == 0)

#define STG_A(t, q) gload_lds16(srcA + (size_t)(t) * 128 + (size_t)(q) * 64 * KB, \
                                smem + ((t) & 1) * 65536 + (q) * 8192 + (tid << 4))
#define STG_B(t, q) gload_lds16(srcB + (size_t)(t) * 128 + (size_t)(q) * 64 * KB, \
                                smem + ((t) & 1) * 65536 + 32768 + (q) * 8192 + (tid << 4))
#define LDF(base, row, s) (*(const bfrag*)((base) + (size_t)(row) * 128 + (((s) * 64 + hib) ^ sw)))
#define MM(I, J, AF, BF) acc[I][J] = __builtin_amdgcn_mfma_f32_16x16x32_bf16(AF, BF, acc[I][J], 0, 0, 0)

// one phase: 12 ds_read_b128, stage issues, barrier, lgkm, 16 MFMA, gate, barrier
#define PH(BUF, MQ, NQ, STAGES, VM) do {                                        \
    const char* Ab_ = smem + (BUF) * 65536;                                     \
    const char* Bb_ = Ab_ + 32768;                                              \
    const int ra_ = wm * 128 + (MQ) * 64 + r;                                   \
    const int rb_ = wn * 64 + (NQ) * 32 + r;                                    \
    bfrag a00_ = LDF(Ab_, ra_,      0), a01_ = LDF(Ab_, ra_,      1);           \
    bfrag a10_ = LDF(Ab_, ra_ + 16, 0), a11_ = LDF(Ab_, ra_ + 16, 1);           \
    bfrag a20_ = LDF(Ab_, ra_ + 32, 0), a21_ = LDF(Ab_, ra_ + 32, 1);           \
    bfrag a30_ = LDF(Ab_, ra_ + 48, 0), a31_ = LDF(Ab_, ra_ + 48, 1);           \
    bfrag b00_ = LDF(Bb_, rb_,      0), b01_ = LDF(Bb_, rb_,      1);           \
    bfrag b10_ = LDF(Bb_, rb_ + 16, 0), b11_ = LDF(Bb_, rb_ + 16, 1);           \
    STAGES;                                                                     \
    __builtin_amdgcn_s_barrier();                                               \
    asm volatile("s_waitcnt lgkmcnt(0)" ::: "memory");                          \
    __builtin_amdgcn_s_setprio(1);                                              \
    MM((MQ)*4 + 0, (NQ)*2 + 0, a00_, b00_); MM((MQ)*4 + 0, (NQ)*2 + 0, a01_, b01_); \
    MM((MQ)*4 + 0, (NQ)*2 + 1, a00_, b10_); MM((MQ)*4 + 0, (NQ)*2 + 1, a01_, b11_); \
    MM((MQ)*4 + 1, (NQ)*2 + 0, a10_, b00_); MM((MQ)*4 + 1, (NQ)*2 + 0, a11_, b01_); \
    MM((MQ)*4 + 1, (NQ)*2 + 1, a10_, b10_); MM((MQ)*4 + 1, (NQ)*2 + 1, a11_, b11_); \
    MM((MQ)*4 + 2, (NQ)*2 + 0, a20_, b00_); MM((MQ)*4 + 2, (NQ)*2 + 0, a21_, b01_); \
    MM((MQ)*4 + 2, (NQ)*2 + 1, a20_, b10_); MM((MQ)*4 + 2, (NQ)*2 + 1, a21_, b11_); \
    MM((MQ)*4 + 3, (NQ)*2 + 0, a30_, b00_); MM((MQ)*4 + 3, (NQ)*2 + 0, a31_, b01_); \
    MM((MQ)*4 + 3, (NQ)*2 + 1, a30_, b10_); MM((MQ)*4 + 3, (NQ)*2 + 1, a31_, b11_); \
    __builtin_amdgcn_s_setprio(0);                                              \
    VM;                                                                         \
    __builtin_amdgcn_s_barrier();                                               \
} while (0)

    // prologue: tile0 fully + tile1 quarters A0,A2; gate leaves 2 in flight.
    STG_A(0, 0); STG_A(0, 1); STG_A(0, 2); STG_A(0, 3);
    STG_B(0, 0); STG_B(0, 1); STG_B(0, 2); STG_B(0, 3);
    STG_A(1, 0); STG_A(1, 2);
    asm volatile("s_waitcnt vmcnt(2)" ::: "memory");
    __builtin_amdgcn_s_barrier();

    // Stage-slot schedule (happens-before safe; every issue is >=1 barrier
    // after its destination region's last ds_read completed):
    //  ph1: tb.A1 tb.A3 tb.B0 | ph2: tb.B1 tb.B2 tb.B3 | ph3: tc.A0 tc.A2
    //  ph4: gate vmcnt(2)     | ph5: tc.A1 tc.A3 tc.B0 | ph6: tc.B1 tc.B2 tc.B3
    //  ph7: td.A0 td.A2       | ph8: gate vmcnt(2)
    for (int it = 0; it < NT / 2; ++it) {
        const int tb = 2 * it + 1;
        int tc = 2 * it + 2; if (tc > NT - 1) tc = NT - 1;   // clamp: idempotent
        int td = 2 * it + 3; if (td > NT - 1) td = NT - 1;   // same-data rewrite
        PH(0, 0, 0, { STG_A(tb, 1); STG_A(tb, 3); STG_B(tb, 0); }, (void)0);
        PH(0, 0, 1, { STG_B(tb, 1); STG_B(tb, 2); STG_B(tb, 3); }, (void)0);
        PH(0, 1, 0, { STG_A(tc, 0); STG_A(tc, 2); }, (void)0);
        PH(0, 1, 1, {}, asm volatile("s_waitcnt vmcnt(2)" ::: "memory"));
        PH(1, 0, 0, { STG_A(tc, 1); STG_A(tc, 3); STG_B(tc, 0); }, (void)0);
        PH(1, 0, 1, { STG_B(tc, 1); STG_B(tc, 2); STG_B(tc, 3); }, (void)0);
        PH(1, 1, 0, { STG_A(td, 0); STG_A(td, 2); }, (void)0);
        PH(1, 1, 1, {}, asm volatile("s_waitcnt vmcnt(2)" ::: "memory"));
    }

#undef PH
#undef MM
#undef LDF
#undef STG_A
#undef STG_B

    // epilogue: C/D layout col = lane&15, row = (lane>>4)*4 + reg
    const int row0 = bm + wm * 128 + (lane >> 4) * 4;
    const int colg = col0 + bnl + wn * 64 + r;
#pragma unroll
    for (int j = 0; j < 4; ++j) {
        const int col = colg + j * 16;
        const float bv = bias[col];
#pragma unroll
        for (int i = 0; i < 8; ++i) {
            const int row = row0 + i * 16;
#pragma unroll
            for (int q = 0; q < 4; ++q)
                C[(size_t)(row + q) * Nout + col] = acc[i][j][q] + bv;
        }
    }
}

// ---- emergency fallback (workspace too small / shape mismatch) -----------
__global__ void naive_kernel(const float* __restrict__ x, const int* __restrict__ Q,
                             const float* __restrict__ scales, const float* __restrict__ zeros,
                             const float* __restrict__ mu1, const float* __restrict__ mu2,
                             const float* __restrict__ bias, float* __restrict__ out,
                             int T, int N, int K, int NG) {
    long long total = (long long)T * K;
    for (long long idx = blockIdx.x * 256ll + threadIdx.x; idx < total;
         idx += (long long)gridDim.x * 256ll) {
        int t = (int)(idx / K);
        int k = (int)(idx - (long long)t * K);
        float s = 0.f;
        for (int n = 0; n < N; n++) {
            int g = n >> 6;
            float w = ((float)Q[(size_t)k * N + n] - zeros[(size_t)k * NG + g]) *
                      scales[(size_t)k * NG + g];
            s += x[(size_t)t * N + n] * w * mu1[n];
        }
        out[idx] = s * mu2[k] + bias[k];
    }
}

extern "C" void kernel_launch(void* const* d_in, const int* in_sizes, int n_in,
                              void* d_out, int out_size, void* d_ws, size_t ws_size,
                              hipStream_t stream) {
    const float* x      = (const float*)d_in[0];
    const int*   Q      = (const int*)d_in[1];
    const float* scales = (const float*)d_in[2];
    const float* zeros  = (const float*)d_in[3];
    const float* mu1    = (const float*)d_in[4];
    const float* mu2    = (const float*)d_in[5];
    const float* bias   = (const float*)d_in[6];
    float* out = (float*)d_out;

    const int N  = in_sizes[4];            // 4096 (contraction)
    const int K  = in_sizes[5];            // 11264 (output cols)
    const int T  = in_sizes[0] / N;        // 4096 (output rows)
    const int NG = in_sizes[2] / K;        // 64 groups

    const size_t xb_bytes  = (size_t)T * N * 2;      // x in bf16
    const size_t row_bytes = (size_t)N * 2;          // one W row in bf16

    const bool shape_ok = (T % 256 == 0) && (K % 256 == 0) &&
                          (N % 128 == 0) && (N % 64 == 0);

    if (!shape_ok || ws_size < xb_bytes + 256 * row_bytes) {
        naive_kernel<<<4096, 256, 0, stream>>>(x, Q, scales, zeros, mu1, mu2,
                                               bias, out, T, N, K, NG);
        return;
    }

    static bool attr_done = false;
    if (!attr_done) {
        (void)hipFuncSetAttribute(reinterpret_cast<const void*>(gemm8p_kernel),
                                  hipFuncAttributeMaxDynamicSharedMemorySize,
                                  131072);
        attr_done = true;
    }

    short* xb = (short*)d_ws;
    short* wb = (short*)((char*)d_ws + xb_bytes);
    size_t max_rows = (ws_size - xb_bytes) / row_bytes;
    int CH = (int)((max_rows / 256) * 256);
    if (CH > K) CH = K;

    cvt_x_kernel<<<(T * N / 16) / 256, 256, 0, stream>>>(x, xb);

    for (int c0 = 0; c0 < K; c0 += CH) {
        int rows = (K - c0 < CH) ? (K - c0) : CH;
        deq_w_kernel<<<rows, 256, 0, stream>>>(Q, scales, zeros, mu1, mu2, wb,
                                               c0, N, NG);
        const int GX = rows / 256;
        dim3 ggrid(GX * (T / 256));
        gemm8p_kernel<<<ggrid, 512, 131072, stream>>>(xb, wb, bias, out,
                                                      N, K, c0, GX);
    }
}

// Round 2
// 684.867 us; speedup vs baseline: 1.1556x; 1.0695x over previous
//
#include <hip/hip_runtime.h>
#include <stdint.h>
#include <stddef.h>

// ---------------------------------------------------------------------------
// InverseImportanceLinear: out = x @ W_deq^T + bias
//   W_deq[k,n] = (Q[k,n] - zeros[k,n/64]) * scales[k,n/64] * mu2[k] * mu1[n]
// Phase 1: dequant W -> bf16 workspace, convert x -> bf16 workspace
//          (perfect 16B-lane-stride coalescing).
// Phase 2: 256x256-tile 8-phase bf16 MFMA GEMM (T2 swizzle + T3/T4 counted
// vmcnt + T5 setprio + T1 XCD swizzle), zigzag fragment-hold so each LDS
// fragment is read exactly once per K-tile (24 ds_read_b128 / wave / K-tile).
// ---------------------------------------------------------------------------

typedef __attribute__((ext_vector_type(8))) short bfrag;   // 8 bf16 = 4 VGPRs
typedef __attribute__((ext_vector_type(4))) short s16x4;   // 4 bf16 = 8 B
typedef __attribute__((ext_vector_type(4))) float f32x4;
typedef __attribute__((ext_vector_type(4))) int   i32x4;

__device__ __forceinline__ short f2bf(float f) {
    uint32_t u = __float_as_uint(f);
    u += 0x7fffu + ((u >> 16) & 1u);        // round-to-nearest-even
    return (short)(u >> 16);
}

__device__ __forceinline__ void gload_lds16(const void* g, void* l) {
    __builtin_amdgcn_global_load_lds(
        (const __attribute__((address_space(1))) void*)g,
        (__attribute__((address_space(3))) void*)l,
        16, 0, 0);
}

// ---- phase 1a: x fp32 -> bf16, 4 elems/thread, lane-stride 16B -----------
__global__ void cvt_x_kernel(const float* __restrict__ x, short* __restrict__ xb,
                             int total4) {
    for (int i = blockIdx.x * 256 + threadIdx.x; i < total4;
         i += gridDim.x * 256) {
        f32x4 a = ((const f32x4*)x)[i];
        s16x4 o;
        o[0] = f2bf(a[0]); o[1] = f2bf(a[1]);
        o[2] = f2bf(a[2]); o[3] = f2bf(a[3]);
        ((s16x4*)xb)[i] = o;
    }
}

// ---- phase 1b: dequant W -> bf16, one block/row, 4 elems/thread/iter -----
__global__ void deq_w_kernel(const int* __restrict__ Q,
                             const float* __restrict__ scales,
                             const float* __restrict__ zeros,
                             const float* __restrict__ mu1,
                             const float* __restrict__ mu2,
                             short* __restrict__ wb,
                             int k0, int N, int NG) {
    const int kl = blockIdx.x;
    const int kg = k0 + kl;
    const float m2 = mu2[kg];
    const int*   qrow = Q + (size_t)kg * N;
    const float* srow = scales + (size_t)kg * NG;
    const float* zrow = zeros + (size_t)kg * NG;
    short*       orow = wb + (size_t)kl * N;
    for (int n0 = threadIdx.x * 4; n0 < N; n0 += 1024) {
        const int g = n0 >> 6;                 // GROUP_SIZE=64
        const float s = srow[g] * m2;
        const float z = zrow[g];
        i32x4 q = *(const i32x4*)(qrow + n0);
        f32x4 u = *(const f32x4*)(mu1 + n0);
        s16x4 o;
        o[0] = f2bf(((float)q[0] - z) * s * u[0]);
        o[1] = f2bf(((float)q[1] - z) * s * u[1]);
        o[2] = f2bf(((float)q[2] - z) * s * u[2]);
        o[3] = f2bf(((float)q[3] - z) * s * u[3]);
        *(s16x4*)(orow + n0) = o;
    }
}

// ---- phase 2: 256x256 8-phase bf16 GEMM, C = A @ B^T + bias --------------
// A: M x Kc bf16 row-major (x). B: rows x Kc bf16 row-major (W chunk).
// 512 threads = 8 waves (2 M x 4 N); per-wave 128x64 output; BK=64.
// LDS 128 KiB: buf{0,1} x { A 32 KiB | B 32 KiB }, XOR-swizzled
// (read byte col ^= (row&7)<<4; inverse swizzle folded into global src).
// Zigzag quadrant order (0,0)->(0,1)->(1,1)->(1,0): A-quadrant held 2
// phases, B0 held 4 phases -> each fragment ds_read exactly once.

__global__ __launch_bounds__(512, 2)
void gemm8p_kernel(const short* __restrict__ A, const short* __restrict__ B,
                   const float* __restrict__ bias, float* __restrict__ C,
                   int Kc, int Nout, int col0, int GX) {
    extern __shared__ __attribute__((aligned(16))) char smem[];   // 131072 B

    const int tid  = threadIdx.x;
    const int lane = tid & 63;
    const int wid  = tid >> 6;
    const int wm   = wid >> 2;              // 0..1
    const int wn   = wid & 3;               // 0..3
    const int r    = lane & 15;
    const int hib  = (lane >> 4) << 4;      // k-fragment byte offset
    const int sw   = (r & 7) << 4;          // read-side XOR swizzle

    // XCD-aware bijective swizzle (grid size is GX*16, multiple of 8)
    const int nwg = (int)gridDim.x;
    const int cpx = nwg >> 3;
    const int bid = (int)blockIdx.x;
    const int swz = (bid & 7) * cpx + (bid >> 3);
    const int bx  = swz % GX;               // over B rows (C cols)
    const int by  = swz / GX;               // over A rows
    const int bm  = by * 256;
    const int bnl = bx * 256;

    const int KB = Kc * 2;                  // row stride in bytes
    // staging source: thread covers row (tid>>3), 16B granule (tid&7),
    // with inverse swizzle folded into the global column.
    const int swcol = ((tid ^ (tid >> 3)) & 7) << 4;
    const char* srcA = (const char*)A + (size_t)(bm  + (tid >> 3)) * KB + swcol;
    const char* srcB = (const char*)B + (size_t)(bnl + (tid >> 3)) * KB + swcol;

    f32x4 acc[8][4];
#pragma unroll
    for (int i = 0; i < 8; i++)
#pragma unroll
        for (int j = 0; j < 4; j++)
            acc[i][j] = (f32x4){0.f, 0.f, 0.f, 0.f};

    const int NT = Kc / 64;                 // K-tiles (even; Kc % 128 == 0)

#define STG_A(t, q) gload_lds16(srcA + (size_t)(t) * 128 + (size_t)(q) * 64 * KB, \
                                smem + ((t) & 1) * 65536 + (q) * 8192 + (tid << 4))
#define STG_B(t, q) gload_lds16(srcB + (size_t)(t) * 128 + (size_t)(q) * 64 * KB, \
                                smem + ((t) & 1) * 65536 + 32768 + (q) * 8192 + (tid << 4))
#define LDF(base, row, s) (*(const bfrag*)((base) + (size_t)(row) * 128 + (((s) * 64 + hib) ^ sw)))
#define MM(I, J, AF, BF) acc[I][J] = __builtin_amdgcn_mfma_f32_16x16x32_bf16(AF, BF, acc[I][J], 0, 0, 0)

#define RD_A(Ab_, MQ) do { const int ra_ = wm * 128 + (MQ) * 64 + r;            \
    Af[0] = LDF(Ab_, ra_,      0); Af[1] = LDF(Ab_, ra_,      1);               \
    Af[2] = LDF(Ab_, ra_ + 16, 0); Af[3] = LDF(Ab_, ra_ + 16, 1);               \
    Af[4] = LDF(Ab_, ra_ + 32, 0); Af[5] = LDF(Ab_, ra_ + 32, 1);               \
    Af[6] = LDF(Ab_, ra_ + 48, 0); Af[7] = LDF(Ab_, ra_ + 48, 1); } while (0)

#define RD_B(Bb_, NQ, BF) do { const int rb_ = wn * 64 + (NQ) * 32 + r;         \
    BF[0] = LDF(Bb_, rb_,      0); BF[1] = LDF(Bb_, rb_,      1);               \
    BF[2] = LDF(Bb_, rb_ + 16, 0); BF[3] = LDF(Bb_, rb_ + 16, 1); } while (0)

// barrier, wait LDS, 16 MFMA on one quadrant (MQ from Af, NQ from BF)
#define QUAD(MQ, NQ, BF) do {                                                   \
    __builtin_amdgcn_s_barrier();                                               \
    asm volatile("s_waitcnt lgkmcnt(0)" ::: "memory");                          \
    __builtin_amdgcn_s_setprio(1);                                              \
    MM((MQ)*4 + 0, (NQ)*2 + 0, Af[0], BF[0]); MM((MQ)*4 + 0, (NQ)*2 + 0, Af[1], BF[1]); \
    MM((MQ)*4 + 0, (NQ)*2 + 1, Af[0], BF[2]); MM((MQ)*4 + 0, (NQ)*2 + 1, Af[1], BF[3]); \
    MM((MQ)*4 + 1, (NQ)*2 + 0, Af[2], BF[0]); MM((MQ)*4 + 1, (NQ)*2 + 0, Af[3], BF[1]); \
    MM((MQ)*4 + 1, (NQ)*2 + 1, Af[2], BF[2]); MM((MQ)*4 + 1, (NQ)*2 + 1, Af[3], BF[3]); \
    MM((MQ)*4 + 2, (NQ)*2 + 0, Af[4], BF[0]); MM((MQ)*4 + 2, (NQ)*2 + 0, Af[5], BF[1]); \
    MM((MQ)*4 + 2, (NQ)*2 + 1, Af[4], BF[2]); MM((MQ)*4 + 2, (NQ)*2 + 1, Af[5], BF[3]); \
    MM((MQ)*4 + 3, (NQ)*2 + 0, Af[6], BF[0]); MM((MQ)*4 + 3, (NQ)*2 + 0, Af[7], BF[1]); \
    MM((MQ)*4 + 3, (NQ)*2 + 1, Af[6], BF[2]); MM((MQ)*4 + 3, (NQ)*2 + 1, Af[7], BF[3]); \
    __builtin_amdgcn_s_setprio(0);                                              \
} while (0)

    // prologue: tile0 fully + tile1 quarters A0,A2; gate leaves 2 in flight.
    STG_A(0, 0); STG_A(0, 1); STG_A(0, 2); STG_A(0, 3);
    STG_B(0, 0); STG_B(0, 1); STG_B(0, 2); STG_B(0, 3);
    STG_A(1, 0); STG_A(1, 2);
    asm volatile("s_waitcnt vmcnt(2)" ::: "memory");
    __builtin_amdgcn_s_barrier();

    bfrag Af[8], B0f[4], B1f[4];

    // Stage-slot schedule identical to verified round-1 kernel; reads are a
    // strict subset timing-wise (every last-read moves earlier), so the
    // happens-before discipline (>=1 barrier between a region's last ds_read
    // and its restage) is preserved. vmcnt gates only at tile-phase p3.
    for (int it = 0; it < NT / 2; ++it) {
        const int tb = 2 * it + 1;
        int tc = 2 * it + 2; if (tc > NT - 1) tc = NT - 1;   // clamp: idempotent
        int td = 2 * it + 3; if (td > NT - 1) td = NT - 1;   // same-data rewrite
        const char* Ab0 = smem;
        const char* Bb0 = smem + 32768;
        const char* Ab1 = smem + 65536;
        const char* Bb1 = smem + 98304;

        // ---- tile even (buf0) ----
        RD_A(Ab0, 0); RD_B(Bb0, 0, B0f);
        STG_A(tb, 1); STG_A(tb, 3); STG_B(tb, 0);
        QUAD(0, 0, B0f);
        __builtin_amdgcn_s_barrier();

        RD_B(Bb0, 1, B1f);
        STG_B(tb, 1); STG_B(tb, 2); STG_B(tb, 3);
        QUAD(0, 1, B1f);
        __builtin_amdgcn_s_barrier();

        RD_A(Ab0, 1);
        STG_A(tc, 0); STG_A(tc, 2);
        QUAD(1, 1, B1f);
        __builtin_amdgcn_s_barrier();

        QUAD(1, 0, B0f);
        asm volatile("s_waitcnt vmcnt(2)" ::: "memory");
        __builtin_amdgcn_s_barrier();

        // ---- tile odd (buf1) ----
        RD_A(Ab1, 0); RD_B(Bb1, 0, B0f);
        STG_A(tc, 1); STG_A(tc, 3); STG_B(tc, 0);
        QUAD(0, 0, B0f);
        __builtin_amdgcn_s_barrier();

        RD_B(Bb1, 1, B1f);
        STG_B(tc, 1); STG_B(tc, 2); STG_B(tc, 3);
        QUAD(0, 1, B1f);
        __builtin_amdgcn_s_barrier();

        RD_A(Ab1, 1);
        STG_A(td, 0); STG_A(td, 2);
        QUAD(1, 1, B1f);
        __builtin_amdgcn_s_barrier();

        QUAD(1, 0, B0f);
        asm volatile("s_waitcnt vmcnt(2)" ::: "memory");
        __builtin_amdgcn_s_barrier();
    }

#undef QUAD
#undef RD_B
#undef RD_A
#undef MM
#undef LDF
#undef STG_B
#undef STG_A

    // epilogue: C/D layout col = lane&15, row = (lane>>4)*4 + reg
    const int row0 = bm + wm * 128 + (lane >> 4) * 4;
    const int colg = col0 + bnl + wn * 64 + r;
#pragma unroll
    for (int j = 0; j < 4; ++j) {
        const int col = colg + j * 16;
        const float bv = bias[col];
#pragma unroll
        for (int i = 0; i < 8; ++i) {
            const int row = row0 + i * 16;
#pragma unroll
            for (int q = 0; q < 4; ++q)
                C[(size_t)(row + q) * Nout + col] = acc[i][j][q] + bv;
        }
    }
}

// ---- emergency fallback (workspace too small / shape mismatch) -----------
__global__ void naive_kernel(const float* __restrict__ x, const int* __restrict__ Q,
                             const float* __restrict__ scales, const float* __restrict__ zeros,
                             const float* __restrict__ mu1, const float* __restrict__ mu2,
                             const float* __restrict__ bias, float* __restrict__ out,
                             int T, int N, int K, int NG) {
    long long total = (long long)T * K;
    for (long long idx = blockIdx.x * 256ll + threadIdx.x; idx < total;
         idx += (long long)gridDim.x * 256ll) {
        int t = (int)(idx / K);
        int k = (int)(idx - (long long)t * K);
        float s = 0.f;
        for (int n = 0; n < N; n++) {
            int g = n >> 6;
            float w = ((float)Q[(size_t)k * N + n] - zeros[(size_t)k * NG + g]) *
                      scales[(size_t)k * NG + g];
            s += x[(size_t)t * N + n] * w * mu1[n];
        }
        out[idx] = s * mu2[k] + bias[k];
    }
}

extern "C" void kernel_launch(void* const* d_in, const int* in_sizes, int n_in,
                              void* d_out, int out_size, void* d_ws, size_t ws_size,
                              hipStream_t stream) {
    const float* x      = (const float*)d_in[0];
    const int*   Q      = (const int*)d_in[1];
    const float* scales = (const float*)d_in[2];
    const float* zeros  = (const float*)d_in[3];
    const float* mu1    = (const float*)d_in[4];
    const float* mu2    = (const float*)d_in[5];
    const float* bias   = (const float*)d_in[6];
    float* out = (float*)d_out;

    const int N  = in_sizes[4];            // 4096 (contraction)
    const int K  = in_sizes[5];            // 11264 (output cols)
    const int T  = in_sizes[0] / N;        // 4096 (output rows)
    const int NG = in_sizes[2] / K;        // 64 groups

    const size_t xb_bytes  = (size_t)T * N * 2;      // x in bf16
    const size_t row_bytes = (size_t)N * 2;          // one W row in bf16

    const bool shape_ok = (T % 256 == 0) && (K % 256 == 0) &&
                          (N % 1024 == 0) && (N % 128 == 0);

    if (!shape_ok || ws_size < xb_bytes + 256 * row_bytes) {
        naive_kernel<<<4096, 256, 0, stream>>>(x, Q, scales, zeros, mu1, mu2,
                                               bias, out, T, N, K, NG);
        return;
    }

    static bool attr_done = false;
    if (!attr_done) {
        (void)hipFuncSetAttribute(reinterpret_cast<const void*>(gemm8p_kernel),
                                  hipFuncAttributeMaxDynamicSharedMemorySize,
                                  131072);
        attr_done = true;
    }

    short* xb = (short*)d_ws;
    short* wb = (short*)((char*)d_ws + xb_bytes);
    size_t max_rows = (ws_size - xb_bytes) / row_bytes;
    int CH = (int)((max_rows / 256) * 256);
    if (CH > K) CH = K;

    cvt_x_kernel<<<2048, 256, 0, stream>>>(x, xb, T * (N / 4));

    for (int c0 = 0; c0 < K; c0 += CH) {
        int rows = (K - c0 < CH) ? (K - c0) : CH;
        deq_w_kernel<<<rows, 256, 0, stream>>>(Q, scales, zeros, mu1, mu2, wb,
                                               c0, N, NG);
        const int GX = rows / 256;
        dim3 ggrid(GX * (T / 256));
        gemm8p_kernel<<<ggrid, 512, 131072, stream>>>(xb, wb, bias, out,
                                                      N, K, c0, GX);
    }
}